// Round 3
// baseline (453.536 us; speedup 1.0000x reference)
//
#include <hip/hip_runtime.h>
#include <hip/hip_bf16.h>

#define BATCH 32
#define SEQ   2048
#define HID   1024
#define M_TOT (BATCH*SEQ)
#define NG    32          // K groups of 32 (each does xh*wh, xh*wl, xl*wh)

typedef __attribute__((ext_vector_type(8))) short          bf16x8;
typedef __attribute__((ext_vector_type(8))) unsigned short us8;
typedef __attribute__((ext_vector_type(4))) float          f32x4;

__device__ __forceinline__ unsigned short f2bf_rn(float x) {
    unsigned u = __float_as_uint(x);
    return (unsigned short)((u + 0x7fffu + ((u >> 16) & 1u)) >> 16);
}
__device__ __forceinline__ float bf2f(unsigned short h) {
    return __uint_as_float(((unsigned)h) << 16);
}

using as1_cv = const __attribute__((address_space(1))) void;
using as3_v  = __attribute__((address_space(3))) void;
__device__ __forceinline__ void gload16(const void* g, char* s) {
    __builtin_amdgcn_global_load_lds((as1_cv*)g, (as3_v*)s, 16, 0, 0);
}

#define FENCE() asm volatile("" ::: "memory")
#define BAR_LG() do { asm volatile("s_waitcnt lgkmcnt(0)" ::: "memory"); \
                      __builtin_amdgcn_s_barrier(); FENCE(); } while (0)
#define BAR_VM4() do { asm volatile("s_waitcnt vmcnt(4) lgkmcnt(0)" ::: "memory"); \
                       __builtin_amdgcn_s_barrier(); FENCE(); } while (0)

#define MFMA_BLK(A4, B4, IB) do { \
  _Pragma("unroll") for (int i_ = 0; i_ < 4; i_++) \
  _Pragma("unroll") for (int j_ = 0; j_ < 4; j_++) \
    acc[(IB) + i_][j_] = __builtin_amdgcn_mfma_f32_16x16x32_bf16(A4[i_], B4[j_], acc[(IB)+i_][j_], 0, 0, 0); \
} while (0)

// ---------------- kernel 0: W f32 -> bf16 hi/lo  w2 = [o][ wh(1024) | wl(1024) ] --
__global__ __launch_bounds__(256) void k_convW(const float* __restrict__ W,
                                               unsigned short* __restrict__ w2) {
    const int i8 = (blockIdx.x * 256 + threadIdx.x) * 8;
    const int o = i8 >> 10, h = i8 & 1023;
    float4 w0 = *(const float4*)(W + i8);
    float4 w1 = *(const float4*)(W + i8 + 4);
    float xs[8] = {w0.x, w0.y, w0.z, w0.w, w1.x, w1.y, w1.z, w1.w};
    us8 hv{}, lv{};
#pragma unroll
    for (int t = 0; t < 8; t++) {
        unsigned short xh = f2bf_rn(xs[t]);
        hv[t] = (unsigned short)xh;
        lv[t] = (unsigned short)f2bf_rn(xs[t] - bf2f(xh));
    }
    *(us8*)(w2 + (size_t)o * 2048 + h)        = hv;
    *(us8*)(w2 + (size_t)o * 2048 + 1024 + h) = lv;
}

// ------ kernel 1: fused (enc+hidden) @ W^T -> tanh -> dot(v) -> pscore16 ------
// LDS: A: slot(2) x [xh|xl] x [256 rows][4 chunks of 16B] -> 64 KB, XOR-swizzled
//      B: 65536 + slot(2) x [wh|wl] x [256][4 chunks]     -> 64 KB, XOR-swizzled
//      hidL: 131072 + 4 KB f32
// Swizzle: 16B-chunk c of row r stored at chunk (c ^ ((r>>1)&3)).
__global__ __launch_bounds__(512, 2) void k_gemm_scores(
    const float* __restrict__ enc,
    const float* __restrict__ hidden,
    const unsigned short* __restrict__ w2,
    const float* __restrict__ b_attn,
    const float* __restrict__ v,
    float* __restrict__ pscore16)
{
    extern __shared__ char smem[];
    float* hidL = (float*)(smem + 131072);

    const int tid  = threadIdx.x;
    const int lane = tid & 63, wid = tid >> 6;
    const int wr = wid >> 2, wc = wid & 3;
    const int fr = lane & 15, g = lane >> 4;
    const int gxr = (fr >> 1) & 3;          // fragment-read XOR (lane-constant)
    const int gsw = (g ^ gxr) * 16;         // swizzled chunk byte offset for reads

    const int bid  = blockIdx.x;
    const int swz  = (bid & 7) * 128 + (bid >> 3);   // XCD-chunk swizzle (bijective, nwg=1024)
    const int mbase = (swz >> 2) * 256;
    const int nbase = (swz & 3) * 256;
    const int bidx  = mbase >> 11;                   // batch (BM=256 divides SEQ)

    // A conversion mapping: thread -> (row, 16-col half)
    const int arow = tid >> 1;
    const int acol = (tid & 1) * 16;
    const int axr  = (arow >> 1) & 3;                // convA write XOR
    const int ao0  = (((tid & 1) * 2) ^ axr) * 16;   // chunk c0 swizzled byte off
    const int ao1  = ao0 ^ 16;                       // chunk c0+1
    const float* encP = enc + (size_t)(mbase + arow) * HID + acol;

    // B gload mapping: dest linear (lane*16); source chunk pre-swizzled
    const int brow  = wid * 16 + (lane >> 2);
    const int bsx8  = ((lane & 3) ^ ((lane >> 3) & 3)) * 8;

    // hidden row -> LDS (1024 f32)
    *(float2*)(hidL + tid * 2) = *(const float2*)(hidden + (size_t)bidx * HID + tid * 2);

    f32x4 acc[8][4];
#pragma unroll
    for (int i = 0; i < 8; i++)
#pragma unroll
        for (int j = 0; j < 4; j++) acc[i][j] = (f32x4)0.f;

    float4 er[4];

    auto loadEnc = [&](int Gn) {
        const float* ep = encP + Gn * 32;
#pragma unroll
        for (int q = 0; q < 4; q++) er[q] = *(const float4*)(ep + q * 4);
    };
    auto convA = [&](int Gn) {
        char* ap = smem + (Gn & 1) * 32768 + arow * 64;
        const float* hp = hidL + Gn * 32 + acol;
        us8 hv0{}, hv1{}, lv0{}, lv1{};
#pragma unroll
        for (int q = 0; q < 4; q++) {
            float4 e = er[q];
            float4 h = *(const float4*)(hp + q * 4);
            float xs[4] = {e.x + h.x, e.y + h.y, e.z + h.z, e.w + h.w};
#pragma unroll
            for (int t = 0; t < 4; t++) {
                unsigned short xh = f2bf_rn(xs[t]);
                unsigned short xl = f2bf_rn(xs[t] - bf2f(xh));
                const int p = q * 4 + t;
                if (p < 8) { hv0[p] = xh; lv0[p] = xl; }
                else       { hv1[p - 8] = xh; lv1[p - 8] = xl; }
            }
        }
        *(us8*)(ap + ao0)          = hv0;
        *(us8*)(ap + ao1)          = hv1;
        *(us8*)(ap + 16384 + ao0)  = lv0;
        *(us8*)(ap + 16384 + ao1)  = lv1;
    };
    auto stageB = [&](int G2, int part) {   // part: 0=wh, 1=wl ; 2 gloads
        const unsigned short* s0 = w2 + (size_t)(nbase + brow) * 2048 + part * 1024 + G2 * 32 + bsx8;
        char* d0 = smem + 65536 + (G2 & 1) * 32768 + part * 16384 + wid * 1024;
        gload16(s0, d0);
        gload16(s0 + (size_t)128 * 2048, d0 + 8192);
    };
    auto rdA = [&](int slot, int part, int i) -> bf16x8 {
        return *(const bf16x8*)(smem + slot * 32768 + part * 16384 +
                                (wr * 128 + i * 16 + fr) * 64 + gsw);
    };
    auto rdB = [&](int slot, int part, int j) -> bf16x8 {
        return *(const bf16x8*)(smem + 65536 + slot * 32768 + part * 16384 +
                                (wc * 64 + j * 16 + fr) * 64 + gsw);
    };

    // ---- prologue ----
    loadEnc(0);
    stageB(0, 0); stageB(0, 1);
    stageB(1, 0); stageB(1, 1);
    asm volatile("s_waitcnt lgkmcnt(0)" ::: "memory");   // hidL ready
    __builtin_amdgcn_s_barrier(); FENCE();
    convA(0);                                            // compiler drains enc(0)
    loadEnc(1);

    bf16x8 aa[4], bh[4], bl[4];

    for (int G = 0; G < NG; ++G) {
        const int slot = G & 1;
        // ---------- ph1: read xh(i0-3) + wh + wl; MFMA xh*wh lo ----------
        BAR_VM4();                                       // B(G) complete, B(G+1) in flight
#pragma unroll
        for (int i = 0; i < 4; i++) aa[i] = rdA(slot, 0, i);
#pragma unroll
        for (int j = 0; j < 4; j++) bh[j] = rdB(slot, 0, j);
#pragma unroll
        for (int j = 0; j < 4; j++) bl[j] = rdB(slot, 1, j);
        __builtin_amdgcn_s_setprio(1);
        MFMA_BLK(aa, bh, 0);
        __builtin_amdgcn_s_setprio(0);
        // ---------- ph2: issue B wh(G+2); MFMA xh*wl lo ----------
        BAR_LG();
        if (G + 2 < NG) stageB(G + 2, 0);
        __builtin_amdgcn_s_setprio(1);
        MFMA_BLK(aa, bl, 0);
        __builtin_amdgcn_s_setprio(0);
        // ---------- ph3: read xh(i4-7); issue B wl(G+2); MFMA xh*wh hi ----------
        BAR_LG();
#pragma unroll
        for (int i = 0; i < 4; i++) aa[i] = rdA(slot, 0, 4 + i);
        if (G + 2 < NG) stageB(G + 2, 1);
        __builtin_amdgcn_s_setprio(1);
        MFMA_BLK(aa, bh, 4);
        __builtin_amdgcn_s_setprio(0);
        // ---------- ph4: convert+write A(G+1); issue enc(G+2); MFMA xh*wl hi ----------
        BAR_LG();
        if (G + 1 < NG) convA(G + 1);
        if (G + 2 < NG) loadEnc(G + 2);
        __builtin_amdgcn_s_setprio(1);
        MFMA_BLK(aa, bl, 4);
        __builtin_amdgcn_s_setprio(0);
        // ---------- ph5: read xl(i0-3); MFMA xl*wh lo ----------
        BAR_LG();
#pragma unroll
        for (int i = 0; i < 4; i++) aa[i] = rdA(slot, 1, i);
        __builtin_amdgcn_s_setprio(1);
        MFMA_BLK(aa, bh, 0);
        __builtin_amdgcn_s_setprio(0);
        // ---------- ph6: read xl(i4-7); MFMA xl*wh hi ----------
        BAR_LG();
#pragma unroll
        for (int i = 0; i < 4; i++) aa[i] = rdA(slot, 1, 4 + i);
        __builtin_amdgcn_s_setprio(1);
        MFMA_BLK(aa, bh, 4);
        __builtin_amdgcn_s_setprio(0);
    }

    // ---- epilogue: tanh(e+b)*v, reduce over cols, write 1 plane per (nblk,wc) ----
    float rs[8][4];
#pragma unroll
    for (int i = 0; i < 8; i++)
#pragma unroll
        for (int r = 0; r < 4; r++) rs[i][r] = 0.f;

#pragma unroll
    for (int j = 0; j < 4; j++) {
        const int n = nbase + wc * 64 + j * 16 + fr;
        const float ba = b_attn[n];
        const float vv = v[n];
#pragma unroll
        for (int i = 0; i < 8; i++)
#pragma unroll
            for (int r = 0; r < 4; r++) {
                float e  = acc[i][j][r] + ba;
                float ex = __expf(2.f * e);
                rs[i][r] += (1.f - 2.f / (ex + 1.f)) * vv;
            }
    }
#pragma unroll
    for (int off = 1; off < 16; off <<= 1)
#pragma unroll
        for (int i = 0; i < 8; i++)
#pragma unroll
            for (int r = 0; r < 4; r++) rs[i][r] += __shfl_xor(rs[i][r], off, 64);

    float v0 = 0.f, v1 = 0.f;
#pragma unroll
    for (int i = 0; i < 4; i++)
#pragma unroll
        for (int r = 0; r < 4; r++)
            if (fr == i * 4 + r) { v0 = rs[i][r]; v1 = rs[i + 4][r]; }

    const int plane = (swz & 3) * 4 + wc;
    const size_t pb = (size_t)plane * M_TOT + mbase + wr * 128 + g * 4 + (fr & 3);
    pscore16[pb + (fr >> 2) * 16]      = v0;
    pscore16[pb + (fr >> 2) * 16 + 64] = v1;
}

// ---------------- kernel 2: sum 16 partial planes + softmax over S ----------
__global__ __launch_bounds__(256) void k_softmax(const float* __restrict__ ps,
                                                 float* __restrict__ out) {
    const int b = blockIdx.x, t = threadIdx.x;
    __shared__ float red[8];
    float loc[8];
    float lmax = -1e30f;
#pragma unroll
    for (int i = 0; i < 8; i++) {
        const int s = t + i * 256;
        float sc = 0.f;
#pragma unroll
        for (int p = 0; p < 16; p++) sc += ps[(size_t)p * M_TOT + (size_t)b * SEQ + s];
        loc[i] = sc;
        lmax = fmaxf(lmax, sc);
    }
    for (int o = 32; o; o >>= 1) lmax = fmaxf(lmax, __shfl_xor(lmax, o, 64));
    if ((t & 63) == 0) red[t >> 6] = lmax;
    __syncthreads();
    const float bmax = fmaxf(fmaxf(red[0], red[1]), fmaxf(red[2], red[3]));
    float ev[8], lsum = 0.f;
#pragma unroll
    for (int i = 0; i < 8; i++) { ev[i] = expf(loc[i] - bmax); lsum += ev[i]; }
    for (int o = 32; o; o >>= 1) lsum += __shfl_xor(lsum, o, 64);
    __syncthreads();
    if ((t & 63) == 0) red[4 + (t >> 6)] = lsum;
    __syncthreads();
    const float inv = 1.f / (red[4] + red[5] + red[6] + red[7]);
#pragma unroll
    for (int i = 0; i < 8; i++)
        out[(size_t)BATCH * HID + (size_t)b * SEQ + t + i * 256] = ev[i] * inv;
}

// ---------------- kernel 3: partial context over S-chunks -------------------
__global__ __launch_bounds__(256) void k_pctx(const float* __restrict__ enc,
                                              const float* __restrict__ attn,
                                              float* __restrict__ pctx) {
    const int hc = blockIdx.x, scb = blockIdx.y, b = blockIdx.z;
    const int h = hc * 256 + threadIdx.x;
    const float* ap = attn + (size_t)b * SEQ + scb * 256;
    const float* ep = enc + ((size_t)b * SEQ + scb * 256) * HID + h;
    float a = 0.f;
#pragma unroll 4
    for (int s = 0; s < 256; s++) a += ap[s] * ep[(size_t)s * HID];
    pctx[((size_t)scb * BATCH + b) * HID + h] = a;
}

// ---------------- kernel 4: reduce partial contexts -------------------------
__global__ __launch_bounds__(256) void k_ctx(const float* __restrict__ pctx,
                                             float* __restrict__ out) {
    const int i = blockIdx.x * 256 + threadIdx.x;
    float a = 0.f;
#pragma unroll
    for (int p = 0; p < 8; p++) a += pctx[(size_t)p * BATCH * HID + i];
    out[i] = a;
}

extern "C" void kernel_launch(void* const* d_in, const int* in_sizes, int n_in,
                              void* d_out, int out_size, void* d_ws, size_t ws_size,
                              hipStream_t stream) {
    const float* hidden = (const float*)d_in[0];
    const float* enc    = (const float*)d_in[1];
    const float* W      = (const float*)d_in[2];
    const float* b_attn = (const float*)d_in[3];
    const float* v      = (const float*)d_in[4];
    float* out = (float*)d_out;

    char* ws = (char*)d_ws;
    unsigned short* w2 = (unsigned short*)ws;                 // 4 MB (dead after gemm)
    float* pscore16    = (float*)(ws + ((size_t)4 << 20));    // 4 MB
    float* pctx        = (float*)ws;                          // reuses w2 region post-gemm

    const int smemBytes = 131072 + 4096;
    hipFuncSetAttribute((const void*)k_gemm_scores,
                        hipFuncAttributeMaxDynamicSharedMemorySize, smemBytes);

    k_convW<<<dim3(512), dim3(256), 0, stream>>>(W, w2);
    k_gemm_scores<<<dim3(1024), dim3(512), smemBytes, stream>>>(
        enc, hidden, w2, b_attn, v, pscore16);
    k_softmax<<<dim3(BATCH), dim3(256), 0, stream>>>(pscore16, out);
    k_pctx<<<dim3(4, 8, BATCH), dim3(256), 0, stream>>>(enc, out + BATCH * HID, pctx);
    k_ctx<<<dim3(128), dim3(256), 0, stream>>>(pctx, out);
}

// Round 4
// 405.117 us; speedup vs baseline: 1.1195x; 1.1195x over previous
//
#include <hip/hip_runtime.h>
#include <hip/hip_bf16.h>

#define BATCH 32
#define SEQ   2048
#define HID   1024
#define M_TOT (BATCH*SEQ)
#define NG    32          // K groups of 32 (each does xh*wh, xh*wl, xl*wh)

typedef __attribute__((ext_vector_type(8))) short          bf16x8;
typedef __attribute__((ext_vector_type(8))) unsigned short us8;
typedef __attribute__((ext_vector_type(4))) float          f32x4;

__device__ __forceinline__ unsigned short f2bf_rn(float x) {
    unsigned u = __float_as_uint(x);
    return (unsigned short)((u + 0x7fffu + ((u >> 16) & 1u)) >> 16);
}
__device__ __forceinline__ float bf2f(unsigned short h) {
    return __uint_as_float(((unsigned)h) << 16);
}
// packed f32x2 -> bf16x2 (lo <- s0, hi <- s1), RTNE on gfx950
__device__ __forceinline__ unsigned cvt_pk_bf16(float s0, float s1) {
    unsigned r;
    asm("v_cvt_pk_bf16_f32 %0, %1, %2" : "=v"(r) : "v"(s0), "v"(s1));
    return r;
}

using as1_cv = const __attribute__((address_space(1))) void;
using as3_v  = __attribute__((address_space(3))) void;
__device__ __forceinline__ void gload16(const void* g, char* s) {
    __builtin_amdgcn_global_load_lds((as1_cv*)g, (as3_v*)s, 16, 0, 0);
}

#define FENCE() asm volatile("" ::: "memory")
#define BAR_P()  do { FENCE(); __builtin_amdgcn_s_barrier(); FENCE(); } while (0)
#define BAR_LG() do { asm volatile("s_waitcnt lgkmcnt(0)" ::: "memory"); \
                      __builtin_amdgcn_s_barrier(); FENCE(); } while (0)
#define BAR_VM8() do { asm volatile("s_waitcnt vmcnt(8) lgkmcnt(0)" ::: "memory"); \
                       __builtin_amdgcn_s_barrier(); FENCE(); } while (0)

#define MFMA_BLK(A4, B4, IB) do { \
  _Pragma("unroll") for (int i_ = 0; i_ < 4; i_++) \
  _Pragma("unroll") for (int j_ = 0; j_ < 4; j_++) \
    acc[(IB) + i_][j_] = __builtin_amdgcn_mfma_f32_16x16x32_bf16(A4[i_], B4[j_], acc[(IB)+i_][j_], 0, 0, 0); \
} while (0)

// ---------------- kernel 0: W f32 -> bf16 hi/lo  w2 = [o][ wh(1024) | wl(1024) ] --
__global__ __launch_bounds__(256) void k_convW(const float* __restrict__ W,
                                               unsigned short* __restrict__ w2) {
    const int i8 = (blockIdx.x * 256 + threadIdx.x) * 8;
    const int o = i8 >> 10, h = i8 & 1023;
    float4 w0 = *(const float4*)(W + i8);
    float4 w1 = *(const float4*)(W + i8 + 4);
    float xs[8] = {w0.x, w0.y, w0.z, w0.w, w1.x, w1.y, w1.z, w1.w};
    us8 hv{}, lv{};
#pragma unroll
    for (int t = 0; t < 8; t++) {
        unsigned short xh = f2bf_rn(xs[t]);
        hv[t] = (unsigned short)xh;
        lv[t] = (unsigned short)f2bf_rn(xs[t] - bf2f(xh));
    }
    *(us8*)(w2 + (size_t)o * 2048 + h)        = hv;
    *(us8*)(w2 + (size_t)o * 2048 + 1024 + h) = lv;
}

// ------ kernel 1: fused (enc+hidden) @ W^T -> tanh -> dot(v) -> pscore16 ------
// LDS: A: slot(2) x [xh|xl] x [256 rows][4 chunks of 16B] -> 64 KB, XOR-swizzled
//      B: 65536 + slot(2) x [wh|wl] x [256][4 chunks]     -> 64 KB, XOR-swizzled
//      hidL: 131072 + 4 KB f32
// Swizzle: 16B-chunk c of row r stored at chunk (c ^ ((r>>1)&3)).
__global__ __launch_bounds__(512, 2) void k_gemm_scores(
    const float* __restrict__ enc,
    const float* __restrict__ hidden,
    const unsigned short* __restrict__ w2,
    const float* __restrict__ b_attn,
    const float* __restrict__ v,
    float* __restrict__ pscore16)
{
    extern __shared__ char smem[];
    float* hidL = (float*)(smem + 131072);

    const int tid  = threadIdx.x;
    const int lane = tid & 63, wid = tid >> 6;
    const int wr = wid >> 2, wc = wid & 3;
    const int fr = lane & 15, g = lane >> 4;
    const int gxr = (fr >> 1) & 3;          // fragment-read XOR (lane-constant)
    const int gsw = (g ^ gxr) * 16;         // swizzled chunk byte offset for reads

    const int bid  = blockIdx.x;
    const int swz  = (bid & 7) * 128 + (bid >> 3);   // XCD-chunk swizzle (bijective, nwg=1024)
    const int mbase = (swz >> 2) * 256;
    const int nbase = (swz & 3) * 256;
    const int bidx  = mbase >> 11;                   // batch (BM=256 divides SEQ)

    // A conversion mapping: thread -> (row, 16-col half)
    const int arow = tid >> 1;
    const int acol = (tid & 1) * 16;
    const int axr  = (arow >> 1) & 3;                // convA write XOR
    const int ao0  = (((tid & 1) * 2) ^ axr) * 16;   // chunk c0 swizzled byte off
    const int ao1  = ao0 ^ 16;                       // chunk c0+1
    const float* encP = enc + (size_t)(mbase + arow) * HID + acol;

    // B gload mapping: dest linear (lane*16); source chunk pre-swizzled
    const int brow  = wid * 16 + (lane >> 2);
    const int bsx8  = ((lane & 3) ^ ((lane >> 3) & 3)) * 8;

    // hidden row -> LDS (1024 f32)
    *(float2*)(hidL + tid * 2) = *(const float2*)(hidden + (size_t)bidx * HID + tid * 2);

    f32x4 acc[8][4];
#pragma unroll
    for (int i = 0; i < 8; i++)
#pragma unroll
        for (int j = 0; j < 4; j++) acc[i][j] = (f32x4)0.f;

    float4 er[4];

    auto loadEnc = [&](int Gn) {
        const float* ep = encP + Gn * 32;
#pragma unroll
        for (int q = 0; q < 4; q++) er[q] = *(const float4*)(ep + q * 4);
    };
    // cvt_pk-based hi/lo split: x -> xh(bf16) + xl(bf16), results packed 2/u32
    auto convA = [&](int Gn) {
        char* ap = smem + (Gn & 1) * 32768 + arow * 64;
        const float* hp = hidL + Gn * 32 + acol;
        unsigned hpk[8], lpk[8];
#pragma unroll
        for (int q = 0; q < 4; q++) {
            float4 e = er[q];
            float4 h = *(const float4*)(hp + q * 4);
            float x0 = e.x + h.x, x1 = e.y + h.y;
            float x2 = e.z + h.z, x3 = e.w + h.w;
            unsigned p01 = cvt_pk_bf16(x0, x1);
            unsigned p23 = cvt_pk_bf16(x2, x3);
            float h0 = __uint_as_float(p01 << 16);
            float h1 = __uint_as_float(p01 & 0xffff0000u);
            float h2 = __uint_as_float(p23 << 16);
            float h3 = __uint_as_float(p23 & 0xffff0000u);
            hpk[q * 2]     = p01;
            hpk[q * 2 + 1] = p23;
            lpk[q * 2]     = cvt_pk_bf16(x0 - h0, x1 - h1);
            lpk[q * 2 + 1] = cvt_pk_bf16(x2 - h2, x3 - h3);
        }
        *(uint4*)(ap + ao0)          = make_uint4(hpk[0], hpk[1], hpk[2], hpk[3]);
        *(uint4*)(ap + ao1)          = make_uint4(hpk[4], hpk[5], hpk[6], hpk[7]);
        *(uint4*)(ap + 16384 + ao0)  = make_uint4(lpk[0], lpk[1], lpk[2], lpk[3]);
        *(uint4*)(ap + 16384 + ao1)  = make_uint4(lpk[4], lpk[5], lpk[6], lpk[7]);
    };
    auto stageB = [&](int G2, int part) {   // part: 0=wh, 1=wl ; 2 gloads
        const unsigned short* s0 = w2 + (size_t)(nbase + brow) * 2048 + part * 1024 + G2 * 32 + bsx8;
        char* d0 = smem + 65536 + (G2 & 1) * 32768 + part * 16384 + wid * 1024;
        gload16(s0, d0);
        gload16(s0 + (size_t)128 * 2048, d0 + 8192);
    };
    auto rdA = [&](int slot, int part, int i) -> bf16x8 {
        return *(const bf16x8*)(smem + slot * 32768 + part * 16384 +
                                (wr * 128 + i * 16 + fr) * 64 + gsw);
    };
    auto rdB = [&](int slot, int part, int j) -> bf16x8 {
        return *(const bf16x8*)(smem + 65536 + slot * 32768 + part * 16384 +
                                (wc * 64 + j * 16 + fr) * 64 + gsw);
    };

    // ---- prologue ----
    loadEnc(0);
    stageB(0, 0); stageB(0, 1);
    stageB(1, 0); stageB(1, 1);
    asm volatile("s_waitcnt lgkmcnt(0)" ::: "memory");   // hidL visible
    __builtin_amdgcn_s_barrier(); FENCE();
    convA(0);                                            // compiler drains enc(0) first
    loadEnc(1);

    bf16x8 aa[4], aa2[4], bh[4], bl[4];

    for (int G = 0; G < NG; ++G) {
        const int slot = G & 1;
        const int Gs = (G + 2 < NG) ? G + 2 : G;         // tail: restage into dead slot
        const int Ge = (G + 2 < NG) ? G + 2 : NG - 1;    // tail: clamp (er unused)
        // ---------- top: B(G) ready; convA(G) writes visible ----------
        BAR_VM8();
        // ---------- ph1: read xh-lo + wh + wl; MFMA xh-lo*wh -> acc[0..3] ----------
#pragma unroll
        for (int i = 0; i < 4; i++) aa[i] = rdA(slot, 0, i);
#pragma unroll
        for (int j = 0; j < 4; j++) bh[j] = rdB(slot, 0, j);
#pragma unroll
        for (int j = 0; j < 4; j++) bl[j] = rdB(slot, 1, j);
        __builtin_amdgcn_s_setprio(1);
        MFMA_BLK(aa, bh, 0);
        __builtin_amdgcn_s_setprio(0);
        // ph1-end: full drain (ph2's DMA re-targets the B bytes ph1 just read)
        BAR_LG();
        // ---------- ph2: stage wh(G+2); MFMA xh-lo*wl -> acc[0..3] ----------
        stageB(Gs, 0);
        __builtin_amdgcn_s_setprio(1);
        MFMA_BLK(aa, bl, 0);
        __builtin_amdgcn_s_setprio(0);
        BAR_P();
        // ---------- ph3: read xh-hi; stage wl(G+2); MFMA xh-hi*wh -> acc[4..7] ----------
#pragma unroll
        for (int i = 0; i < 4; i++) aa2[i] = rdA(slot, 0, 4 + i);
        stageB(Gs, 1);
        __builtin_amdgcn_s_setprio(1);
        MFMA_BLK(aa2, bh, 4);
        __builtin_amdgcn_s_setprio(0);
        BAR_P();
        // ---------- ph4: convA(G+1) -> slot^1; enc(G+2); MFMA xh-hi*wl -> acc[4..7] ----------
        if (G + 1 < NG) convA(G + 1);
        loadEnc(Ge);
        __builtin_amdgcn_s_setprio(1);
        MFMA_BLK(aa2, bl, 4);
        __builtin_amdgcn_s_setprio(0);
        BAR_P();
        // ---------- ph5: read xl-lo; MFMA xl-lo*wh -> acc[0..3] ----------
#pragma unroll
        for (int i = 0; i < 4; i++) aa[i] = rdA(slot, 1, i);
        __builtin_amdgcn_s_setprio(1);
        MFMA_BLK(aa, bh, 0);
        __builtin_amdgcn_s_setprio(0);
        // ---------- ph6: read xl-hi; MFMA xl-hi*wh -> acc[4..7] (no barrier) ----------
#pragma unroll
        for (int i = 0; i < 4; i++) aa2[i] = rdA(slot, 1, 4 + i);
        __builtin_amdgcn_s_setprio(1);
        MFMA_BLK(aa2, bh, 4);
        __builtin_amdgcn_s_setprio(0);
    }

    // ---- epilogue: tanh(e+b)*v, reduce over cols, write 1 plane per (nblk,wc) ----
    float rs[8][4];
#pragma unroll
    for (int i = 0; i < 8; i++)
#pragma unroll
        for (int r = 0; r < 4; r++) rs[i][r] = 0.f;

#pragma unroll
    for (int j = 0; j < 4; j++) {
        const int n = nbase + wc * 64 + j * 16 + fr;
        const float ba = b_attn[n];
        const float vv = v[n];
#pragma unroll
        for (int i = 0; i < 8; i++)
#pragma unroll
            for (int r = 0; r < 4; r++) {
                float e  = acc[i][j][r] + ba;
                float ex = __expf(2.f * e);
                rs[i][r] += (1.f - 2.f / (ex + 1.f)) * vv;
            }
    }
#pragma unroll
    for (int off = 1; off < 16; off <<= 1)
#pragma unroll
        for (int i = 0; i < 8; i++)
#pragma unroll
            for (int r = 0; r < 4; r++) rs[i][r] += __shfl_xor(rs[i][r], off, 64);

    float v0 = 0.f, v1 = 0.f;
#pragma unroll
    for (int i = 0; i < 4; i++)
#pragma unroll
        for (int r = 0; r < 4; r++)
            if (fr == i * 4 + r) { v0 = rs[i][r]; v1 = rs[i + 4][r]; }

    const int plane = (swz & 3) * 4 + wc;
    const size_t pb = (size_t)plane * M_TOT + mbase + wr * 128 + g * 4 + (fr & 3);
    pscore16[pb + (fr >> 2) * 16]      = v0;
    pscore16[pb + (fr >> 2) * 16 + 64] = v1;
}

// ---------------- kernel 2: sum 16 partial planes + softmax over S ----------
__global__ __launch_bounds__(256) void k_softmax(const float* __restrict__ ps,
                                                 float* __restrict__ out) {
    const int b = blockIdx.x, t = threadIdx.x;
    __shared__ float red[8];
    float loc[8];
    float lmax = -1e30f;
#pragma unroll
    for (int i = 0; i < 8; i++) {
        const int s = t + i * 256;
        float sc = 0.f;
#pragma unroll
        for (int p = 0; p < 16; p++) sc += ps[(size_t)p * M_TOT + (size_t)b * SEQ + s];
        loc[i] = sc;
        lmax = fmaxf(lmax, sc);
    }
    for (int o = 32; o; o >>= 1) lmax = fmaxf(lmax, __shfl_xor(lmax, o, 64));
    if ((t & 63) == 0) red[t >> 6] = lmax;
    __syncthreads();
    const float bmax = fmaxf(fmaxf(red[0], red[1]), fmaxf(red[2], red[3]));
    float ev[8], lsum = 0.f;
#pragma unroll
    for (int i = 0; i < 8; i++) { ev[i] = expf(loc[i] - bmax); lsum += ev[i]; }
    for (int o = 32; o; o >>= 1) lsum += __shfl_xor(lsum, o, 64);
    __syncthreads();
    if ((t & 63) == 0) red[4 + (t >> 6)] = lsum;
    __syncthreads();
    const float inv = 1.f / (red[4] + red[5] + red[6] + red[7]);
#pragma unroll
    for (int i = 0; i < 8; i++)
        out[(size_t)BATCH * HID + (size_t)b * SEQ + t + i * 256] = ev[i] * inv;
}

// ---------------- kernel 3: partial context over S-chunks -------------------
__global__ __launch_bounds__(256) void k_pctx(const float* __restrict__ enc,
                                              const float* __restrict__ attn,
                                              float* __restrict__ pctx) {
    const int hc = blockIdx.x, scb = blockIdx.y, b = blockIdx.z;
    const int h = hc * 256 + threadIdx.x;
    const float* ap = attn + (size_t)b * SEQ + scb * 256;
    const float* ep = enc + ((size_t)b * SEQ + scb * 256) * HID + h;
    float a = 0.f;
#pragma unroll 4
    for (int s = 0; s < 256; s++) a += ap[s] * ep[(size_t)s * HID];
    pctx[((size_t)scb * BATCH + b) * HID + h] = a;
}

// ---------------- kernel 4: reduce partial contexts -------------------------
__global__ __launch_bounds__(256) void k_ctx(const float* __restrict__ pctx,
                                             float* __restrict__ out) {
    const int i = blockIdx.x * 256 + threadIdx.x;
    float a = 0.f;
#pragma unroll
    for (int p = 0; p < 8; p++) a += pctx[(size_t)p * BATCH * HID + i];
    out[i] = a;
}

extern "C" void kernel_launch(void* const* d_in, const int* in_sizes, int n_in,
                              void* d_out, int out_size, void* d_ws, size_t ws_size,
                              hipStream_t stream) {
    const float* hidden = (const float*)d_in[0];
    const float* enc    = (const float*)d_in[1];
    const float* W      = (const float*)d_in[2];
    const float* b_attn = (const float*)d_in[3];
    const float* v      = (const float*)d_in[4];
    float* out = (float*)d_out;

    char* ws = (char*)d_ws;
    unsigned short* w2 = (unsigned short*)ws;                 // 4 MB (dead after gemm)
    float* pscore16    = (float*)(ws + ((size_t)4 << 20));    // 4 MB
    float* pctx        = (float*)ws;                          // reuses w2 region post-gemm

    const int smemBytes = 131072 + 4096;
    hipFuncSetAttribute((const void*)k_gemm_scores,
                        hipFuncAttributeMaxDynamicSharedMemorySize, smemBytes);

    k_convW<<<dim3(512), dim3(256), 0, stream>>>(W, w2);
    k_gemm_scores<<<dim3(1024), dim3(512), smemBytes, stream>>>(
        enc, hidden, w2, b_attn, v, pscore16);
    k_softmax<<<dim3(BATCH), dim3(256), 0, stream>>>(pscore16, out);
    k_pctx<<<dim3(4, 8, BATCH), dim3(256), 0, stream>>>(enc, out + BATCH * HID, pctx);
    k_ctx<<<dim3(128), dim3(256), 0, stream>>>(pctx, out);
}